// Round 4
// baseline (49.998 us; speedup 1.0000x reference)
//
#include <hip/hip_runtime.h>

// Problem dims (fixed by the reference)
#define BB 2
#define LL 1024
#define DI 1536
#define DS 16
#define TPB 256

#define LOG2E 1.44269504088896340736f

__device__ __forceinline__ float exp2_fast(float x) { return __builtin_amdgcn_exp2f(x); }

// ---------------------------------------------------------------------------
// Pass 1: thread <-> (b, d, chunk); all 16 n-states in registers.
// Stores per-chunk: sdt = sum(delta) (n-independent decay summary) and
// Bacc[n]:  x_after = exp2(Av2[n]*sdt)*x_before + Bacc[n]
// Layouts (d-minor, fully coalesced): sdt [c][b][d], bsum [c][b][n][d]
// ---------------------------------------------------------------------------
template <int NCc>
__global__ __launch_bounds__(TPB) void ss1(
    const float* __restrict__ u, const float* __restrict__ delta,
    const float* __restrict__ A, const float* __restrict__ Bm,
    float* __restrict__ sdt_out, float* __restrict__ bsum)
{
    constexpr int CLc = LL / NCc;
    const int d = blockIdx.x * TPB + threadIdx.x;
    const int c = blockIdx.y;
    const int b = blockIdx.z;

    float Av2[DS];
    {
        const float4* Ap = (const float4*)(A + d * DS);
        #pragma unroll
        for (int q = 0; q < 4; ++q) {
            const float4 av = Ap[q];
            Av2[q*4+0] = av.x * LOG2E; Av2[q*4+1] = av.y * LOG2E;
            Av2[q*4+2] = av.z * LOG2E; Av2[q*4+3] = av.w * LOG2E;
        }
    }

    const size_t bl0 = (size_t)b * LL + (size_t)c * CLc;
    const float* __restrict__ dp = delta + bl0 * DI + d;
    const float* __restrict__ up = u     + bl0 * DI + d;
    const float* __restrict__ bp = Bm    + bl0 * DS;      // wave-uniform -> s_load

    float dt[CLc], uu[CLc];
    #pragma unroll
    for (int i = 0; i < CLc; ++i) {
        dt[i] = dp[(size_t)i * DI];
        uu[i] = up[(size_t)i * DI];
    }

    float Bacc[DS];
    #pragma unroll
    for (int n = 0; n < DS; ++n) Bacc[n] = 0.0f;
    float sdt = 0.0f;

    #pragma unroll
    for (int i = 0; i < CLc; ++i) {
        const float du = dt[i] * uu[i];
        sdt += dt[i];
        const float* __restrict__ bt = bp + i * DS;
        #pragma unroll
        for (int n = 0; n < DS; ++n) {
            const float a = exp2_fast(dt[i] * Av2[n]);
            Bacc[n] = fmaf(a, Bacc[n], du * bt[n]);
        }
    }

    sdt_out[((size_t)c * BB + b) * DI + d] = sdt;
    float* __restrict__ sp = bsum + ((size_t)c * BB + b) * DS * DI + d;
    #pragma unroll
    for (int n = 0; n < DS; ++n) sp[(size_t)n * DI] = Bacc[n];  // coalesced per n
}

// ---------------------------------------------------------------------------
// Pass 1.5: exclusive scan over chunks per (b,d,n).
// Thread -> (b,n,d) with d minor; all per-c accesses coalesced.
// ---------------------------------------------------------------------------
template <int NCc>
__global__ __launch_bounds__(TPB) void ss_scan(
    const float* __restrict__ A,
    const float* __restrict__ sdt_in, const float* __restrict__ bsum,
    float* __restrict__ xin)
{
    const int gid = blockIdx.x * TPB + threadIdx.x;   // ((b*DS+n)*DI+d)
    const int d   = gid % DI;
    const int bn  = gid / DI;
    const int n   = bn & 15;
    const int b   = bn >> 4;
    const float Av2 = A[d * DS + n] * LOG2E;

    const size_t cstr = (size_t)BB * DS * DI;
    const size_t sstr = (size_t)BB * DI;
    const size_t soff = (size_t)b * DI + d;

    float x = 0.0f;
    #pragma unroll 8
    for (int c = 0; c < NCc; ++c) {
        xin[(size_t)c * cstr + gid] = x;      // state BEFORE chunk c
        const float a = exp2_fast(Av2 * sdt_in[(size_t)c * sstr + soff]);
        x = fmaf(a, x, bsum[(size_t)c * cstr + gid]);
    }
}

// ---------------------------------------------------------------------------
// Pass 2: thread <-> (b, d, chunk); load incoming state (coalesced),
// re-run chunk, reduce over n in registers, write y (coalesced).
// ---------------------------------------------------------------------------
template <int NCc>
__global__ __launch_bounds__(TPB) void ss2(
    const float* __restrict__ u, const float* __restrict__ delta,
    const float* __restrict__ A, const float* __restrict__ Bm,
    const float* __restrict__ Cm, const float* __restrict__ Dv,
    const float* __restrict__ xin, float* __restrict__ y)
{
    constexpr int CLc = LL / NCc;
    const int d = blockIdx.x * TPB + threadIdx.x;
    const int c = blockIdx.y;
    const int b = blockIdx.z;

    float Av2[DS];
    {
        const float4* Ap = (const float4*)(A + d * DS);
        #pragma unroll
        for (int q = 0; q < 4; ++q) {
            const float4 av = Ap[q];
            Av2[q*4+0] = av.x * LOG2E; Av2[q*4+1] = av.y * LOG2E;
            Av2[q*4+2] = av.z * LOG2E; Av2[q*4+3] = av.w * LOG2E;
        }
    }

    float x[DS];
    {
        const float* __restrict__ xp = xin + ((size_t)c * BB + b) * DS * DI + d;
        #pragma unroll
        for (int n = 0; n < DS; ++n) x[n] = xp[(size_t)n * DI];  // coalesced per n
    }

    const float Dd = Dv[d];

    const size_t bl0 = (size_t)b * LL + (size_t)c * CLc;
    const float* __restrict__ dp = delta + bl0 * DI + d;
    const float* __restrict__ up = u     + bl0 * DI + d;
    const float* __restrict__ bp = Bm    + bl0 * DS;   // uniform
    const float* __restrict__ cp = Cm    + bl0 * DS;   // uniform
    float* __restrict__ yp       = y     + bl0 * DI + d;

    float dt[CLc], uu[CLc];
    #pragma unroll
    for (int i = 0; i < CLc; ++i) {
        dt[i] = dp[(size_t)i * DI];
        uu[i] = up[(size_t)i * DI];
    }

    #pragma unroll
    for (int i = 0; i < CLc; ++i) {
        const float du = dt[i] * uu[i];
        const float* __restrict__ bt = bp + i * DS;
        const float* __restrict__ ct = cp + i * DS;
        float y0 = 0.0f, y1 = 0.0f;
        #pragma unroll
        for (int n = 0; n < DS; ++n) {
            const float a = exp2_fast(dt[i] * Av2[n]);
            x[n] = fmaf(a, x[n], du * bt[n]);
            if (n & 1) y1 = fmaf(x[n], ct[n], y1);
            else       y0 = fmaf(x[n], ct[n], y0);
        }
        yp[(size_t)i * DI] = fmaf(uu[i], Dd, y0 + y1);
    }
}

// Fallback: streaming serial scan (no workspace needed)
__global__ __launch_bounds__(TPB) void ss_serial(
    const float* __restrict__ u, const float* __restrict__ delta,
    const float* __restrict__ A, const float* __restrict__ Bm,
    const float* __restrict__ Cm, const float* __restrict__ Dv,
    float* __restrict__ y)
{
    const int d = blockIdx.x * TPB + threadIdx.x;
    const int b = blockIdx.z;

    float Av2[DS];
    #pragma unroll
    for (int n = 0; n < DS; ++n) Av2[n] = A[d * DS + n] * LOG2E;

    float x[DS];
    #pragma unroll
    for (int n = 0; n < DS; ++n) x[n] = 0.0f;

    const float Dd = Dv[d];
    const size_t bl0 = (size_t)b * LL;
    const float* __restrict__ dp = delta + bl0 * DI + d;
    const float* __restrict__ up = u     + bl0 * DI + d;
    const float* __restrict__ bp = Bm    + bl0 * DS;
    const float* __restrict__ cp = Cm    + bl0 * DS;
    float* __restrict__ yp       = y     + bl0 * DI + d;

    for (int t = 0; t < LL; ++t) {
        const float dt = dp[(size_t)t * DI];
        const float uu = up[(size_t)t * DI];
        const float du = dt * uu;
        const float* __restrict__ bt = bp + t * DS;
        const float* __restrict__ ct = cp + t * DS;
        float y0 = 0.0f, y1 = 0.0f;
        #pragma unroll
        for (int n = 0; n < DS; ++n) {
            const float a = exp2_fast(dt * Av2[n]);
            x[n] = fmaf(a, x[n], du * bt[n]);
            if (n & 1) y1 = fmaf(x[n], ct[n], y1);
            else       y0 = fmaf(x[n], ct[n], y0);
        }
        yp[(size_t)t * DI] = fmaf(uu, Dd, y0 + y1);
    }
}

template <int NCc>
static void launch_chunked(const float* u, const float* delta, const float* A,
                           const float* Bm, const float* Cm, const float* Dv,
                           float* y, void* d_ws, hipStream_t stream) {
    const size_t sdt_bytes  = (size_t)NCc * BB * DI * sizeof(float);
    const size_t bsum_bytes = (size_t)NCc * BB * DI * DS * sizeof(float);

    float* sdt  = (float*)d_ws;
    float* bsum = (float*)((char*)d_ws + sdt_bytes);
    float* xin  = (float*)((char*)d_ws + sdt_bytes + bsum_bytes);

    dim3 grid1(DI / TPB, NCc, BB);
    ss1<NCc><<<grid1, TPB, 0, stream>>>(u, delta, A, Bm, sdt, bsum);

    dim3 gridS((BB * DI * DS) / TPB, 1, 1);
    ss_scan<NCc><<<gridS, TPB, 0, stream>>>(A, sdt, bsum, xin);

    ss2<NCc><<<grid1, TPB, 0, stream>>>(u, delta, A, Bm, Cm, Dv, xin, y);
}

extern "C" void kernel_launch(void* const* d_in, const int* in_sizes, int n_in,
                              void* d_out, int out_size, void* d_ws, size_t ws_size,
                              hipStream_t stream) {
    const float* u     = (const float*)d_in[0];
    const float* delta = (const float*)d_in[1];
    const float* A     = (const float*)d_in[2];
    const float* Bm    = (const float*)d_in[3];
    const float* Cm    = (const float*)d_in[4];
    const float* Dv    = (const float*)d_in[5];
    float* y = (float*)d_out;

    auto need = [](int nc) {
        return (size_t)nc * BB * DI * sizeof(float) +            // sdt
               2 * (size_t)nc * BB * DI * DS * sizeof(float);    // bsum + xin
    };

    if (ws_size >= need(128)) {
        launch_chunked<128>(u, delta, A, Bm, Cm, Dv, y, d_ws, stream);
    } else if (ws_size >= need(64)) {
        launch_chunked<64>(u, delta, A, Bm, Cm, Dv, y, d_ws, stream);
    } else {
        dim3 grid(DI / TPB, 1, BB);
        ss_serial<<<grid, TPB, 0, stream>>>(u, delta, A, Bm, Cm, Dv, y);
    }
}